// Round 10
// baseline (323.345 us; speedup 1.0000x reference)
//
#include <hip/hip_runtime.h>
#include <math.h>

#define D 128
#define NNODES 8192
#define NEDGES 16384
#define NSTEMS 4096
#define NGRAPHS 256
#define NSTEPS 12
#define OPS 105
#define SLOPE 0.01f
#define MT 32              // nodes per mega-block
#define NBLK (NNODES / MT) // 256 blocks == 256 CUs, all co-resident
#define LDA 136            // padded halfs per LDS row (h/m tiles)
#define LDA2 264           // padded halfs per LDS row (stem cat tile)
#define LDQ 40             // padded halfs per Qh row

typedef _Float16 half_t;
typedef __attribute__((ext_vector_type(8))) _Float16 f16x8;
typedef __attribute__((ext_vector_type(4))) float f32x4;

__device__ __forceinline__ float leaky(float x) { return x > 0.f ? x : SLOPE * x; }
__device__ __forceinline__ float fast_sigmoid(float x) {
    return __builtin_amdgcn_rcpf(1.f + __expf(-x));
}
__device__ __forceinline__ float fast_tanh(float x) {
    float e = __expf(2.f * x);
    return 1.f - 2.f * __builtin_amdgcn_rcpf(e + 1.f);
}

// ---------------- setup: pack weights + transpose g1 + zero scratch ----------------
// B-frag 16x16x32: lane L supplies B[k = kt*32 + (L>>4)*8 + j][n = nt*16 + (L&15)], j=0..7.
__global__ void k_setup(
    const float* __restrict__ root, const float* __restrict__ wih,
    const float* __restrict__ whh, const float* __restrict__ bond,
    const float* __restrict__ sw1, const float* __restrict__ sw2,
    const float* __restrict__ sw3, const float* __restrict__ bw1,
    const float* __restrict__ bw2, const float* __restrict__ gw1,
    half_t* __restrict__ rootP, half_t* __restrict__ WihP,
    half_t* __restrict__ WhhP, half_t* __restrict__ bondTP,
    half_t* __restrict__ s1P, half_t* __restrict__ s2P, half_t* __restrict__ s3P,
    half_t* __restrict__ w1P, half_t* __restrict__ w2P, half_t* __restrict__ bondQP,
    float* __restrict__ g1T, int* __restrict__ zeroi) {
    int idx = blockIdx.x * 256 + threadIdx.x;
    int which = blockIdx.y;
    if (which == 10) {
        if (idx < 128 * 128) {
            int r = idx >> 7, c = idx & 127;
            g1T[c * 128 + r] = gw1[idx];
        }
        return;
    }
    if (which == 11) {   // zero deg + fill + barrier counters (12*16)
        if (idx < 2 * NNODES + 256) zeroi[idx] = 0;
        return;
    }
    int KT = (which == 4) ? 8 : (which == 9) ? 1 : 4;
    int NT = (which == 1 || which == 2) ? 24 : (which == 3) ? 2 : (which == 6) ? 7 : 8;
    if (idx >= NT * KT * 512) return;
    int j = idx & 7;
    int L = (idx >> 3) & 63;
    int t = idx >> 9;
    int kt = t % KT, nt = t / KT;
    int k = kt * 32 + (L >> 4) * 8 + j;
    int n = nt * 16 + (L & 15);
    switch (which) {
        case 0: rootP[idx] = (half_t)root[k * D + n]; break;
        case 1: WihP[idx] = (half_t)wih[n * D + k]; break;
        case 2: WhhP[idx] = (half_t)whh[n * D + k]; break;
        case 3: bondTP[idx] = (half_t)bond[n * D + k]; break;
        case 4: s1P[idx] = (half_t)sw1[n * 256 + k]; break;
        case 5: s2P[idx] = (half_t)sw2[n * 128 + k]; break;
        case 6: s3P[idx] = (n < OPS) ? (half_t)sw3[n * 128 + k] : (half_t)0.f; break;
        case 7: w1P[idx] = (half_t)bw1[n * D + k]; break;
        case 8: w2P[idx] = (half_t)bw2[n * D + k]; break;
        case 9: bondQP[idx] = (half_t)bond[k * D + n]; break;
    }
}

__global__ void k_deg(const int* __restrict__ eidx, int* __restrict__ deg) {
    int e = blockIdx.x * 256 + threadIdx.x;
    if (e < NEDGES) atomicAdd(&deg[eidx[NEDGES + e]], 1);
}

__global__ void k_scan(const int* __restrict__ deg, int* __restrict__ row_start,
                       float* __restrict__ inv_deg) {
    __shared__ int sums[256];
    int t = threadIdx.x;
    int base = t * 32;
    int s = 0;
    for (int k = 0; k < 32; ++k) s += deg[base + k];
    sums[t] = s;
    __syncthreads();
    for (int off = 1; off < 256; off <<= 1) {
        int v = sums[t];
        int u = (t >= off) ? sums[t - off] : 0;
        __syncthreads();
        sums[t] = v + u;
        __syncthreads();
    }
    int run = sums[t] - s;
    for (int k = 0; k < 32; ++k) {
        int d = deg[base + k];
        row_start[base + k] = run;
        run += d;
        inv_deg[base + k] = (d > 0) ? (1.0f / (float)d) : 0.0f;
    }
    if (t == 255) row_start[NNODES] = run;
}

// CSR-ordered packed edges: epack[pos] = {src, a0, a1, dst}
__global__ void k_scatter(const int* __restrict__ eidx, const int* __restrict__ eattr,
                          const int* __restrict__ row_start,
                          int* __restrict__ fill, int4* __restrict__ epack) {
    int e = blockIdx.x * 256 + threadIdx.x;
    if (e < NEDGES) {
        int d = eidx[NEDGES + e];
        int pos = row_start[d] + atomicAdd(&fill[d], 1);
        int2 aa = *(const int2*)(eattr + 2 * e);
        epack[pos] = make_int4(eidx[e], aa.x, aa.y, d);
    }
}

// ---------------- persistent kernel: init MLP + P0 + 12 steps ----------------
// 256 blocks x 512 threads, all co-resident. Block owns 32 nodes.
// h lives in regs + LDS across all steps (no global h traffic until the end).
// Cross-block data: ONLY P, via agent-scope (L2-bypass, IF$-coherent) atomics.
// Pipelined barrier: conv+gh (own-block work) run BEFORE the wait; arrival uses
// 16-way spread counters to avoid same-line atomic serialization.
__global__ __launch_bounds__(512, 2) void k_mega(
    const int* __restrict__ x, const float* __restrict__ embBlock,
    const half_t* __restrict__ w1P, const float* __restrict__ b1v,
    const half_t* __restrict__ w2P, const float* __restrict__ b2v,
    float* __restrict__ hF,
    float* __restrict__ P0, float* __restrict__ P1,
    const half_t* __restrict__ rootP, const half_t* __restrict__ WihP,
    const half_t* __restrict__ WhhP, const half_t* __restrict__ bondTP,
    const half_t* __restrict__ bondQP,
    const float* __restrict__ cbias, const float* __restrict__ bih,
    const float* __restrict__ bhh,
    const int4* __restrict__ epack,
    const int* __restrict__ row_start, const float* __restrict__ inv_deg,
    int* __restrict__ ctr) {
    __shared__ __align__(16) half_t As[MT * LDA];
    __shared__ __align__(16) half_t Am[MT * LDA];
    __shared__ __align__(16) half_t Qh[MT * LDQ];
    __shared__ float Q[MT * 32];

    const int tid = threadIdx.x;
    const int w = tid >> 6;
    const int lane = tid & 63;
    const int quad = lane >> 4;
    const int l16 = lane & 15;
    const int n0 = blockIdx.x * MT;
    const int c = w * 16 + l16;

    // ---- prologue 1: emb -> As (fp16) ----
    {
        int row = tid >> 4;
        int col = (tid & 15) * 8;
        const float* src = embBlock + (size_t)x[n0 + row] * D + col;
        float4 v0 = ((const float4*)src)[0];
        float4 v1 = ((const float4*)src)[1];
        f16x8 hv;
        hv[0] = (half_t)v0.x; hv[1] = (half_t)v0.y; hv[2] = (half_t)v0.z; hv[3] = (half_t)v0.w;
        hv[4] = (half_t)v1.x; hv[5] = (half_t)v1.y; hv[6] = (half_t)v1.z; hv[7] = (half_t)v1.w;
        *(f16x8*)&As[row * LDA + col] = hv;
    }
    __syncthreads();

    // ---- prologue 2: init MLP L1 -> Am ----
    {
        f32x4 acc[2] = {{0.f, 0.f, 0.f, 0.f}, {0.f, 0.f, 0.f, 0.f}};
#pragma unroll
        for (int kt = 0; kt < 4; ++kt) {
            f16x8 b = *(const f16x8*)(w1P + (size_t)((w * 4 + kt) * 64 + lane) * 8);
            f16x8 a0 = *(const f16x8*)&As[(0 + l16) * LDA + kt * 32 + quad * 8];
            f16x8 a1 = *(const f16x8*)&As[(16 + l16) * LDA + kt * 32 + quad * 8];
            acc[0] = __builtin_amdgcn_mfma_f32_16x16x32_f16(a0, b, acc[0], 0, 0, 0);
            acc[1] = __builtin_amdgcn_mfma_f32_16x16x32_f16(a1, b, acc[1], 0, 0, 0);
        }
        float bb = b1v[c];
        __syncthreads();
#pragma unroll
        for (int mt = 0; mt < 2; ++mt)
#pragma unroll
            for (int r = 0; r < 4; ++r)
                Am[(mt * 16 + quad * 4 + r) * LDA + c] = (half_t)leaky(acc[mt][r] + bb);
    }
    __syncthreads();

    // ---- prologue 3: init MLP L2 -> h regs + As ----
    float h[2][4];
    {
        f32x4 acc[2] = {{0.f, 0.f, 0.f, 0.f}, {0.f, 0.f, 0.f, 0.f}};
#pragma unroll
        for (int kt = 0; kt < 4; ++kt) {
            f16x8 b = *(const f16x8*)(w2P + (size_t)((w * 4 + kt) * 64 + lane) * 8);
            f16x8 a0 = *(const f16x8*)&Am[(0 + l16) * LDA + kt * 32 + quad * 8];
            f16x8 a1 = *(const f16x8*)&Am[(16 + l16) * LDA + kt * 32 + quad * 8];
            acc[0] = __builtin_amdgcn_mfma_f32_16x16x32_f16(a0, b, acc[0], 0, 0, 0);
            acc[1] = __builtin_amdgcn_mfma_f32_16x16x32_f16(a1, b, acc[1], 0, 0, 0);
        }
        float bb = b2v[c];
#pragma unroll
        for (int mt = 0; mt < 2; ++mt)
#pragma unroll
            for (int r = 0; r < 4; ++r) {
                int row = mt * 16 + quad * 4 + r;
                float hv = acc[mt][r] + bb;
                h[mt][r] = hv;
                As[row * LDA + c] = (half_t)hv;
            }
    }
    Q[tid] = 0.f;
    Q[tid + 512] = 0.f;
    __syncthreads();

    // ---- prologue 4: P0 = h0 @ bond^T (waves 0..3), then arrive bar[0] ----
    if (w < 4) {
        int mt = w >> 1, nt = w & 1;
        f32x4 acc = {0.f, 0.f, 0.f, 0.f};
#pragma unroll
        for (int kt = 0; kt < 4; ++kt) {
            f16x8 b = *(const f16x8*)(bondTP + (size_t)((nt * 4 + kt) * 64 + lane) * 8);
            f16x8 a = *(const f16x8*)&As[(mt * 16 + l16) * LDA + kt * 32 + quad * 8];
            acc = __builtin_amdgcn_mfma_f32_16x16x32_f16(a, b, acc, 0, 0, 0);
        }
#pragma unroll
        for (int r = 0; r < 4; ++r)
            __hip_atomic_store(&P0[(size_t)(n0 + mt * 16 + quad * 4 + r) * 32 + nt * 16 + l16],
                               acc[r], __ATOMIC_RELAXED, __HIP_MEMORY_SCOPE_AGENT);
    }

    // ---- one-time loads: weights -> regs, edge -> regs, constants ----
    f16x8 rootB[4], ghB[12], giB[12], aggB;
#pragma unroll
    for (int kt = 0; kt < 4; ++kt)
        rootB[kt] = *(const f16x8*)(rootP + (size_t)((w * 4 + kt) * 64 + lane) * 8);
#pragma unroll
    for (int kt = 0; kt < 4; ++kt)
#pragma unroll
        for (int g = 0; g < 3; ++g) {
            ghB[g * 4 + kt] = *(const f16x8*)(WhhP + (size_t)(((g * 8 + w) * 4 + kt) * 64 + lane) * 8);
            giB[g * 4 + kt] = *(const f16x8*)(WihP + (size_t)(((g * 8 + w) * 4 + kt) * 64 + lane) * 8);
        }
    aggB = *(const f16x8*)(bondQP + (size_t)(w * 64 + lane) * 8);
    const int p0 = row_start[n0];
    const int p1 = row_start[n0 + MT];
    int4 ep;
    const bool have = (p0 + tid < p1);
    if (have) ep = epack[p0 + tid];
    const float cb = cbias[c];
    const float bi0 = bih[c], bi1 = bih[D + c], bi2 = bih[2 * D + c];
    const float bh0 = bhh[c], bh1 = bhh[D + c], bh2 = bhh[2 * D + c];
    const int qrow0 = tid >> 5, qrow1 = (tid + 512) >> 5;
    const float idg0 = inv_deg[n0 + qrow0];
    const float idg1 = inv_deg[n0 + qrow1];

    __syncthreads();   // drains vmcnt: P0 stores visible at IF$
    if (tid == 0)
        __hip_atomic_fetch_add(&ctr[0 * 16 + (blockIdx.x & 15)], 1,
                               __ATOMIC_RELEASE, __HIP_MEMORY_SCOPE_AGENT);

    for (int s = 0; s < NSTEPS; ++s) {
        const float* __restrict__ Pprev = (s & 1) ? P1 : P0;
        float* __restrict__ Pnext = (s & 1) ? P0 : P1;

        // --- own-block work BEFORE the wait: conv + gh MFMAs (hides barrier skew) ---
        f32x4 convAcc[2] = {{0.f, 0.f, 0.f, 0.f}, {0.f, 0.f, 0.f, 0.f}};
        f32x4 ghA[2][3];
#pragma unroll
        for (int mt = 0; mt < 2; ++mt)
#pragma unroll
            for (int g = 0; g < 3; ++g) ghA[mt][g] = f32x4{0.f, 0.f, 0.f, 0.f};
#pragma unroll
        for (int kt = 0; kt < 4; ++kt) {
            f16x8 a0 = *(const f16x8*)&As[(0 + l16) * LDA + kt * 32 + quad * 8];
            f16x8 a1 = *(const f16x8*)&As[(16 + l16) * LDA + kt * 32 + quad * 8];
            convAcc[0] = __builtin_amdgcn_mfma_f32_16x16x32_f16(a0, rootB[kt], convAcc[0], 0, 0, 0);
            convAcc[1] = __builtin_amdgcn_mfma_f32_16x16x32_f16(a1, rootB[kt], convAcc[1], 0, 0, 0);
#pragma unroll
            for (int g = 0; g < 3; ++g) {
                ghA[0][g] = __builtin_amdgcn_mfma_f32_16x16x32_f16(a0, ghB[g * 4 + kt], ghA[0][g], 0, 0, 0);
                ghA[1][g] = __builtin_amdgcn_mfma_f32_16x16x32_f16(a1, ghB[g * 4 + kt], ghA[1][g], 0, 0, 0);
            }
        }

        // --- wait bar[s]: P_s ready (16-way spread counters) ---
        if (tid == 0) {
            for (;;) {
                int sum = 0;
#pragma unroll
                for (int i = 0; i < 16; ++i)
                    sum += __hip_atomic_load(&ctr[s * 16 + i],
                                             __ATOMIC_RELAXED, __HIP_MEMORY_SCOPE_AGENT);
                if (sum >= NBLK) break;
                __builtin_amdgcn_s_sleep(1);
            }
        }
        __syncthreads();

        // --- edge gathers (agent-scope) -> Q (LDS atomics) ---
        if (have) {
            float wv = __hip_atomic_load(&Pprev[(size_t)ep.x * 32 + ep.y],
                                         __ATOMIC_RELAXED, __HIP_MEMORY_SCOPE_AGENT);
            atomicAdd(&Q[(ep.w - n0) * 32 + ep.z], wv);
        }
        for (int p = p0 + tid + 512; p < p1; p += 512) {
            int4 e2 = epack[p];
            float wv = __hip_atomic_load(&Pprev[(size_t)e2.x * 32 + e2.y],
                                         __ATOMIC_RELAXED, __HIP_MEMORY_SCOPE_AGENT);
            atomicAdd(&Q[(e2.w - n0) * 32 + e2.z], wv);
        }
        __syncthreads();   // Q complete

        // --- Q -> fp16 (x inv_deg), re-zero ---
        Qh[qrow0 * LDQ + (tid & 31)] = (half_t)(Q[tid] * idg0);
        Qh[qrow1 * LDQ + (tid & 31)] = (half_t)(Q[tid + 512] * idg1);
        Q[tid] = 0.f;
        Q[tid + 512] = 0.f;
        __syncthreads();

        // --- agg MFMA + m -> Am ---
#pragma unroll
        for (int mt = 0; mt < 2; ++mt) {
            f32x4 acc = {0.f, 0.f, 0.f, 0.f};
            f16x8 a = *(const f16x8*)&Qh[(mt * 16 + l16) * LDQ + quad * 8];
            acc = __builtin_amdgcn_mfma_f32_16x16x32_f16(a, aggB, acc, 0, 0, 0);
#pragma unroll
            for (int r = 0; r < 4; ++r) {
                float m = convAcc[mt][r] + cb + acc[r];
                Am[(mt * 16 + quad * 4 + r) * LDA + c] = (half_t)leaky(m);
            }
        }
        __syncthreads();

        // --- gi MFMAs + GRU combine -> h regs + As ---
        f32x4 giA[2][3];
#pragma unroll
        for (int mt = 0; mt < 2; ++mt)
#pragma unroll
            for (int g = 0; g < 3; ++g) giA[mt][g] = f32x4{0.f, 0.f, 0.f, 0.f};
#pragma unroll
        for (int kt = 0; kt < 4; ++kt) {
            f16x8 a0 = *(const f16x8*)&Am[(0 + l16) * LDA + kt * 32 + quad * 8];
            f16x8 a1 = *(const f16x8*)&Am[(16 + l16) * LDA + kt * 32 + quad * 8];
#pragma unroll
            for (int g = 0; g < 3; ++g) {
                giA[0][g] = __builtin_amdgcn_mfma_f32_16x16x32_f16(a0, giB[g * 4 + kt], giA[0][g], 0, 0, 0);
                giA[1][g] = __builtin_amdgcn_mfma_f32_16x16x32_f16(a1, giB[g * 4 + kt], giA[1][g], 0, 0, 0);
            }
        }
#pragma unroll
        for (int mt = 0; mt < 2; ++mt) {
#pragma unroll
            for (int r = 0; r < 4; ++r) {
                int row = mt * 16 + quad * 4 + r;
                float rg = fast_sigmoid(giA[mt][0][r] + bi0 + ghA[mt][0][r] + bh0);
                float z = fast_sigmoid(giA[mt][1][r] + bi1 + ghA[mt][1][r] + bh1);
                float nn = fast_tanh(giA[mt][2][r] + bi2 + rg * (ghA[mt][2][r] + bh2));
                float hnew = (1.f - z) * nn + z * h[mt][r];
                h[mt][r] = hnew;
                As[row * LDA + c] = (half_t)hnew;
            }
        }

        if (s < NSTEPS - 1) {
            __syncthreads();   // As complete for P MFMA
            if (w < 4) {
                int mt = w >> 1, nt = w & 1;
                f32x4 acc = {0.f, 0.f, 0.f, 0.f};
#pragma unroll
                for (int kt = 0; kt < 4; ++kt) {
                    f16x8 b = *(const f16x8*)(bondTP + (size_t)((nt * 4 + kt) * 64 + lane) * 8);
                    f16x8 a = *(const f16x8*)&As[(mt * 16 + l16) * LDA + kt * 32 + quad * 8];
                    acc = __builtin_amdgcn_mfma_f32_16x16x32_f16(a, b, acc, 0, 0, 0);
                }
#pragma unroll
                for (int r = 0; r < 4; ++r)
                    __hip_atomic_store(&Pnext[(size_t)(n0 + mt * 16 + quad * 4 + r) * 32 + nt * 16 + l16],
                                       acc[r], __ATOMIC_RELAXED, __HIP_MEMORY_SCOPE_AGENT);
            }
            __syncthreads();   // drains vmcnt: P stores visible
            if (tid == 0)
                __hip_atomic_fetch_add(&ctr[(s + 1) * 16 + (blockIdx.x & 15)], 1,
                                       __ATOMIC_RELEASE, __HIP_MEMORY_SCOPE_AGENT);
        }
    }

    // ---- epilogue: write final h for the heads ----
#pragma unroll
    for (int mt = 0; mt < 2; ++mt)
#pragma unroll
        for (int r = 0; r < 4; ++r) {
            int row = mt * 16 + quad * 4 + r;
            hF[(size_t)(n0 + row) * D + c] = h[mt][r];
        }
}

// ---------------- stem head (MFMA) + fused gpred ----------------
__device__ __forceinline__ int lower_bound_dev(const int* a, int n, int v) {
    int lo = 0, hi = n;
    while (lo < hi) {
        int m = (lo + hi) >> 1;
        if (a[m] < v) lo = m + 1;
        else hi = m;
    }
    return lo;
}

__global__ __launch_bounds__(512) void k_heads(
    const float* __restrict__ hF, const int* __restrict__ sni, const int* __restrict__ stypes,
    const float* __restrict__ embStem,
    const half_t* __restrict__ s1P, const float* __restrict__ b1,
    const half_t* __restrict__ s2P, const float* __restrict__ b2,
    const half_t* __restrict__ s3P, const float* __restrict__ b3,
    const int* __restrict__ batch,
    const float* __restrict__ g1T, const float* __restrict__ gb1,
    const float* __restrict__ gw2, const float* __restrict__ gb2,
    float* __restrict__ dout) {
    __shared__ __align__(16) half_t cat[16 * LDA2];
    __shared__ __align__(16) half_t t1[16 * LDA];
    __shared__ __align__(16) half_t t2[16 * LDA];
    const int tid = threadIdx.x;
    if (blockIdx.x >= 256) {
        int g = blockIdx.x - 256;
        if (tid >= 128) return;
        __shared__ float mean_s[D];
        __shared__ float red[D];
        int j = tid;
        int lo = lower_bound_dev(batch, NNODES, g);
        int hi = lower_bound_dev(batch, NNODES, g + 1);
        float sum = 0.f;
        for (int n = lo; n < hi; ++n) sum += hF[(size_t)n * D + j];
        float denom = (hi > lo) ? (float)(hi - lo) : 1.0f;
        mean_s[j] = sum / denom;
        __syncthreads();
        float a = gb1[j];
        for (int i = 0; i < D; ++i) a += mean_s[i] * g1T[i * D + j];
        a = leaky(a);
        red[j] = a * gw2[j];
        __syncthreads();
        for (int off = 64; off > 0; off >>= 1) {
            if (j < off) red[j] += red[j + off];
            __syncthreads();
        }
        if (j == 0) dout[NSTEMS * OPS + g] = red[0] + gb2[0];
        return;
    }
    const int w = tid >> 6;
    const int lane = tid & 63;
    const int quad = lane >> 4;
    const int l16 = lane & 15;
    const int s0 = blockIdx.x * 16;
    const int c = w * 16 + l16;

    {
        int row = tid >> 5;
        int col = (tid & 31) * 8;
        const float* src;
        if (col < D) src = hF + (size_t)sni[s0 + row] * D + col;
        else src = embStem + (size_t)stypes[s0 + row] * D + (col - D);
        float4 v0 = ((const float4*)src)[0];
        float4 v1 = ((const float4*)src)[1];
        f16x8 hv;
        hv[0] = (half_t)v0.x; hv[1] = (half_t)v0.y; hv[2] = (half_t)v0.z; hv[3] = (half_t)v0.w;
        hv[4] = (half_t)v1.x; hv[5] = (half_t)v1.y; hv[6] = (half_t)v1.z; hv[7] = (half_t)v1.w;
        *(f16x8*)&cat[row * LDA2 + col] = hv;
    }
    __syncthreads();

    {
        f32x4 acc = {0.f, 0.f, 0.f, 0.f};
#pragma unroll
        for (int kt = 0; kt < 8; ++kt) {
            f16x8 b = *(const f16x8*)(s1P + (size_t)((w * 8 + kt) * 64 + lane) * 8);
            f16x8 a = *(const f16x8*)&cat[l16 * LDA2 + kt * 32 + quad * 8];
            acc = __builtin_amdgcn_mfma_f32_16x16x32_f16(a, b, acc, 0, 0, 0);
        }
        float bb = b1[c];
#pragma unroll
        for (int r = 0; r < 4; ++r)
            t1[(quad * 4 + r) * LDA + c] = (half_t)leaky(acc[r] + bb);
    }
    __syncthreads();
    {
        f32x4 acc = {0.f, 0.f, 0.f, 0.f};
#pragma unroll
        for (int kt = 0; kt < 4; ++kt) {
            f16x8 b = *(const f16x8*)(s2P + (size_t)((w * 4 + kt) * 64 + lane) * 8);
            f16x8 a = *(const f16x8*)&t1[l16 * LDA + kt * 32 + quad * 8];
            acc = __builtin_amdgcn_mfma_f32_16x16x32_f16(a, b, acc, 0, 0, 0);
        }
        float bb = b2[c];
#pragma unroll
        for (int r = 0; r < 4; ++r)
            t2[(quad * 4 + r) * LDA + c] = (half_t)leaky(acc[r] + bb);
    }
    __syncthreads();
    if (w < 7) {
        f32x4 acc = {0.f, 0.f, 0.f, 0.f};
#pragma unroll
        for (int kt = 0; kt < 4; ++kt) {
            f16x8 b = *(const f16x8*)(s3P + (size_t)((w * 4 + kt) * 64 + lane) * 8);
            f16x8 a = *(const f16x8*)&t2[l16 * LDA + kt * 32 + quad * 8];
            acc = __builtin_amdgcn_mfma_f32_16x16x32_f16(a, b, acc, 0, 0, 0);
        }
        int j = w * 16 + l16;
        if (j < OPS) {
            float bb = b3[j];
#pragma unroll
            for (int r = 0; r < 4; ++r)
                dout[(size_t)(s0 + quad * 4 + r) * OPS + j] = acc[r] + bb;
        }
    }
}

// ---------------- launch ----------------
extern "C" void kernel_launch(void* const* d_in, const int* in_sizes, int n_in,
                              void* d_out, int out_size, void* d_ws, size_t ws_size,
                              hipStream_t stream) {
    const int* x = (const int*)d_in[0];
    const int* stypes = (const int*)d_in[1];
    const int* eattr = (const int*)d_in[2];
    const int* eidx = (const int*)d_in[3];
    const int* sni = (const int*)d_in[4];
    const int* batch = (const int*)d_in[5];
    const float* embBlock = (const float*)d_in[6];
    const float* embStem = (const float*)d_in[7];
    const float* embBond = (const float*)d_in[8];
    const float* b2e_w1 = (const float*)d_in[9];
    const float* b2e_b1 = (const float*)d_in[10];
    const float* b2e_w2 = (const float*)d_in[11];
    const float* b2e_b2 = (const float*)d_in[12];
    const float* conv_root = (const float*)d_in[13];
    const float* conv_bias = (const float*)d_in[14];
    const float* gru_w_ih = (const float*)d_in[15];
    const float* gru_w_hh = (const float*)d_in[16];
    const float* gru_b_ih = (const float*)d_in[17];
    const float* gru_b_hh = (const float*)d_in[18];
    const float* s2p_w1 = (const float*)d_in[19];
    const float* s2p_b1 = (const float*)d_in[20];
    const float* s2p_w2 = (const float*)d_in[21];
    const float* s2p_b2 = (const float*)d_in[22];
    const float* s2p_w3 = (const float*)d_in[23];
    const float* s2p_b3 = (const float*)d_in[24];
    const float* g2p_w1 = (const float*)d_in[25];
    const float* g2p_b1 = (const float*)d_in[26];
    const float* g2p_w2 = (const float*)d_in[27];
    const float* g2p_b2 = (const float*)d_in[28];
    float* out_f = (float*)d_out;

    float* W = (float*)d_ws;
    size_t off = 0;
    auto alloc = [&](size_t words) {
        size_t o = off;
        off += (words + 3) & ~(size_t)3;
        return o;
    };
    float* hF = W + alloc(NNODES * D);
    float* P0 = W + alloc(NNODES * 32);
    float* P1 = W + alloc(NNODES * 32);
    half_t* rootP = (half_t*)(W + alloc(16384 / 2));
    half_t* WihP = (half_t*)(W + alloc(49152 / 2));
    half_t* WhhP = (half_t*)(W + alloc(49152 / 2));
    half_t* bondTP = (half_t*)(W + alloc(4096 / 2));
    half_t* s1P = (half_t*)(W + alloc(32768 / 2));
    half_t* s2P = (half_t*)(W + alloc(16384 / 2));
    half_t* s3P = (half_t*)(W + alloc(14336 / 2));
    half_t* w1P = (half_t*)(W + alloc(16384 / 2));
    half_t* w2P = (half_t*)(W + alloc(16384 / 2));
    half_t* bondQP = (half_t*)(W + alloc(4096 / 2));
    float* g1T = W + alloc(128 * 128);
    int* row_start = (int*)(W + alloc(NNODES + 1));
    int4* epack = (int4*)(W + alloc(NEDGES * 4));
    float* inv_deg = W + alloc(NNODES);
    float* zbase = W + alloc(2 * NNODES + 256);   // deg + fill + barrier counters
    int* deg = (int*)zbase;
    int* fill = deg + NNODES;
    int* ctr = fill + NNODES;

    k_setup<<<dim3(192, 12), 256, 0, stream>>>(
        conv_root, gru_w_ih, gru_w_hh, embBond, s2p_w1, s2p_w2, s2p_w3,
        b2e_w1, b2e_w2, g2p_w1,
        rootP, WihP, WhhP, bondTP, s1P, s2P, s3P, w1P, w2P, bondQP,
        g1T, (int*)zbase);
    k_deg<<<(NEDGES + 255) / 256, 256, 0, stream>>>(eidx, deg);
    k_scan<<<1, 256, 0, stream>>>(deg, row_start, inv_deg);
    k_scatter<<<(NEDGES + 255) / 256, 256, 0, stream>>>(eidx, eattr, row_start, fill, epack);

    k_mega<<<NBLK, 512, 0, stream>>>(
        x, embBlock, w1P, b2e_b1, w2P, b2e_b2,
        hF, P0, P1, rootP, WihP, WhhP, bondTP, bondQP,
        conv_bias, gru_b_ih, gru_b_hh,
        epack, row_start, inv_deg, ctr);

    k_heads<<<NSTEMS / 16 + NGRAPHS, 512, 0, stream>>>(
        hF, sni, stypes, embStem,
        s1P, s2p_b1, s2P, s2p_b2, s3P, s2p_b3,
        batch, g1T, g2p_b1, g2p_w2, g2p_b2, out_f);
}

// Round 11
// 283.438 us; speedup vs baseline: 1.1408x; 1.1408x over previous
//
#include <hip/hip_runtime.h>
#include <math.h>

#define D 128
#define NNODES 8192
#define NEDGES 16384
#define NSTEMS 4096
#define NGRAPHS 256
#define NSTEPS 12
#define OPS 105
#define SLOPE 0.01f
#define IMT 32             // nodes per init-block
#define SMT 64             // nodes per step-block
#define NSB (NNODES / SMT) // 128 step blocks x 1024 threads
#define LDA 136            // padded halfs per LDS row (h/m tiles)
#define LDA2 264           // padded halfs per LDS row (stem cat tile)
#define LDQ 40             // padded halfs per Qh row

typedef _Float16 half_t;
typedef __attribute__((ext_vector_type(8))) _Float16 f16x8;
typedef __attribute__((ext_vector_type(4))) float f32x4;

__device__ __forceinline__ float leaky(float x) { return x > 0.f ? x : SLOPE * x; }
__device__ __forceinline__ float fast_sigmoid(float x) {
    return __builtin_amdgcn_rcpf(1.f + __expf(-x));
}
__device__ __forceinline__ float fast_tanh(float x) {
    float e = __expf(2.f * x);
    return 1.f - 2.f * __builtin_amdgcn_rcpf(e + 1.f);
}

// ---------------- setup: pack weights + transpose g1 + zero scratch ----------------
// B-frag 16x16x32: lane L supplies B[k = kt*32 + (L>>4)*8 + j][n = nt*16 + (L&15)], j=0..7.
__global__ void k_setup(
    const float* __restrict__ root, const float* __restrict__ wih,
    const float* __restrict__ whh, const float* __restrict__ bond,
    const float* __restrict__ sw1, const float* __restrict__ sw2,
    const float* __restrict__ sw3, const float* __restrict__ bw1,
    const float* __restrict__ bw2, const float* __restrict__ gw1,
    half_t* __restrict__ rootP, half_t* __restrict__ WihP,
    half_t* __restrict__ WhhP, half_t* __restrict__ bondTP,
    half_t* __restrict__ s1P, half_t* __restrict__ s2P, half_t* __restrict__ s3P,
    half_t* __restrict__ w1P, half_t* __restrict__ w2P, half_t* __restrict__ bondQP,
    float* __restrict__ g1T, int* __restrict__ zeroi) {
    int idx = blockIdx.x * 256 + threadIdx.x;
    int which = blockIdx.y;
    if (which == 10) {
        if (idx < 128 * 128) {
            int r = idx >> 7, c = idx & 127;
            g1T[c * 128 + r] = gw1[idx];
        }
        return;
    }
    if (which == 11) {
        if (idx < 2 * NNODES) zeroi[idx] = 0;
        return;
    }
    int KT = (which == 4) ? 8 : (which == 9) ? 1 : 4;
    int NT = (which == 1 || which == 2) ? 24 : (which == 3) ? 2 : (which == 6) ? 7 : 8;
    if (idx >= NT * KT * 512) return;
    int j = idx & 7;
    int L = (idx >> 3) & 63;
    int t = idx >> 9;
    int kt = t % KT, nt = t / KT;
    int k = kt * 32 + (L >> 4) * 8 + j;
    int n = nt * 16 + (L & 15);
    switch (which) {
        case 0: rootP[idx] = (half_t)root[k * D + n]; break;
        case 1: WihP[idx] = (half_t)wih[n * D + k]; break;
        case 2: WhhP[idx] = (half_t)whh[n * D + k]; break;
        case 3: bondTP[idx] = (half_t)bond[n * D + k]; break;
        case 4: s1P[idx] = (half_t)sw1[n * 256 + k]; break;
        case 5: s2P[idx] = (half_t)sw2[n * 128 + k]; break;
        case 6: s3P[idx] = (n < OPS) ? (half_t)sw3[n * 128 + k] : (half_t)0.f; break;
        case 7: w1P[idx] = (half_t)bw1[n * D + k]; break;
        case 8: w2P[idx] = (half_t)bw2[n * D + k]; break;
        case 9: bondQP[idx] = (half_t)bond[k * D + n]; break;
    }
}

__global__ void k_deg(const int* __restrict__ eidx, int* __restrict__ deg) {
    int e = blockIdx.x * 256 + threadIdx.x;
    if (e < NEDGES) atomicAdd(&deg[eidx[NEDGES + e]], 1);
}

__global__ void k_scan(const int* __restrict__ deg, int* __restrict__ row_start,
                       float* __restrict__ inv_deg) {
    __shared__ int sums[256];
    int t = threadIdx.x;
    int base = t * 32;
    int s = 0;
    for (int k = 0; k < 32; ++k) s += deg[base + k];
    sums[t] = s;
    __syncthreads();
    for (int off = 1; off < 256; off <<= 1) {
        int v = sums[t];
        int u = (t >= off) ? sums[t - off] : 0;
        __syncthreads();
        sums[t] = v + u;
        __syncthreads();
    }
    int run = sums[t] - s;
    for (int k = 0; k < 32; ++k) {
        int d = deg[base + k];
        row_start[base + k] = run;
        run += d;
        inv_deg[base + k] = (d > 0) ? (1.0f / (float)d) : 0.0f;
    }
    if (t == 255) row_start[NNODES] = run;
}

// CSR-ordered packed edges: epack[pos] = {src, a0, a1, dst}
__global__ void k_scatter(const int* __restrict__ eidx, const int* __restrict__ eattr,
                          const int* __restrict__ row_start,
                          int* __restrict__ fill, int4* __restrict__ epack) {
    int e = blockIdx.x * 256 + threadIdx.x;
    if (e < NEDGES) {
        int d = eidx[NEDGES + e];
        int pos = row_start[d] + atomicAdd(&fill[d], 1);
        int2 aa = *(const int2*)(eattr + 2 * e);
        epack[pos] = make_int4(eidx[e], aa.x, aa.y, d);
    }
}

// ---------------- init (MFMA) + fused P0 ----------------
__global__ __launch_bounds__(512, 2) void k_init(
    const int* __restrict__ x, const float* __restrict__ embBlock,
    const half_t* __restrict__ w1P, const float* __restrict__ b1,
    const half_t* __restrict__ w2P, const float* __restrict__ b2,
    const half_t* __restrict__ bondTP,
    float* __restrict__ hF, float* __restrict__ P0) {
    __shared__ __align__(16) half_t Ae[IMT * LDA];
    __shared__ __align__(16) half_t T1[IMT * LDA];
    const int tid = threadIdx.x;
    const int w = tid >> 6;
    const int lane = tid & 63;
    const int quad = lane >> 4;
    const int l16 = lane & 15;
    const int n0 = blockIdx.x * IMT;
    const int c = w * 16 + l16;

    {
        int row = tid >> 4;
        int col = (tid & 15) * 8;
        const float* src = embBlock + (size_t)x[n0 + row] * D + col;
        float4 v0 = ((const float4*)src)[0];
        float4 v1 = ((const float4*)src)[1];
        f16x8 hv;
        hv[0] = (half_t)v0.x; hv[1] = (half_t)v0.y; hv[2] = (half_t)v0.z; hv[3] = (half_t)v0.w;
        hv[4] = (half_t)v1.x; hv[5] = (half_t)v1.y; hv[6] = (half_t)v1.z; hv[7] = (half_t)v1.w;
        *(f16x8*)&Ae[row * LDA + col] = hv;
    }
    __syncthreads();

    {
        f32x4 acc[2] = {{0.f, 0.f, 0.f, 0.f}, {0.f, 0.f, 0.f, 0.f}};
#pragma unroll
        for (int kt = 0; kt < 4; ++kt) {
            f16x8 b = *(const f16x8*)(w1P + (size_t)((w * 4 + kt) * 64 + lane) * 8);
            f16x8 a0 = *(const f16x8*)&Ae[(0 + l16) * LDA + kt * 32 + quad * 8];
            f16x8 a1 = *(const f16x8*)&Ae[(16 + l16) * LDA + kt * 32 + quad * 8];
            acc[0] = __builtin_amdgcn_mfma_f32_16x16x32_f16(a0, b, acc[0], 0, 0, 0);
            acc[1] = __builtin_amdgcn_mfma_f32_16x16x32_f16(a1, b, acc[1], 0, 0, 0);
        }
        float bb = b1[c];
#pragma unroll
        for (int mt = 0; mt < 2; ++mt)
#pragma unroll
            for (int r = 0; r < 4; ++r)
                T1[(mt * 16 + quad * 4 + r) * LDA + c] = (half_t)leaky(acc[mt][r] + bb);
    }
    __syncthreads();

    {
        f32x4 acc[2] = {{0.f, 0.f, 0.f, 0.f}, {0.f, 0.f, 0.f, 0.f}};
#pragma unroll
        for (int kt = 0; kt < 4; ++kt) {
            f16x8 b = *(const f16x8*)(w2P + (size_t)((w * 4 + kt) * 64 + lane) * 8);
            f16x8 a0 = *(const f16x8*)&T1[(0 + l16) * LDA + kt * 32 + quad * 8];
            f16x8 a1 = *(const f16x8*)&T1[(16 + l16) * LDA + kt * 32 + quad * 8];
            acc[0] = __builtin_amdgcn_mfma_f32_16x16x32_f16(a0, b, acc[0], 0, 0, 0);
            acc[1] = __builtin_amdgcn_mfma_f32_16x16x32_f16(a1, b, acc[1], 0, 0, 0);
        }
        float bb = b2[c];
#pragma unroll
        for (int mt = 0; mt < 2; ++mt)
#pragma unroll
            for (int r = 0; r < 4; ++r) {
                int row = mt * 16 + quad * 4 + r;
                float h = acc[mt][r] + bb;
                hF[(size_t)(n0 + row) * D + c] = h;
                Ae[row * LDA + c] = (half_t)h;
            }
    }
    __syncthreads();

    if (w < 4) {   // P0 = h0 @ bond^T
        int mt = w >> 1, nt = w & 1;
        f32x4 acc = {0.f, 0.f, 0.f, 0.f};
#pragma unroll
        for (int kt = 0; kt < 4; ++kt) {
            f16x8 b = *(const f16x8*)(bondTP + (size_t)((nt * 4 + kt) * 64 + lane) * 8);
            f16x8 a = *(const f16x8*)&Ae[(mt * 16 + l16) * LDA + kt * 32 + quad * 8];
            acc = __builtin_amdgcn_mfma_f32_16x16x32_f16(a, b, acc, 0, 0, 0);
        }
#pragma unroll
        for (int r = 0; r < 4; ++r)
            P0[(size_t)(n0 + mt * 16 + quad * 4 + r) * 32 + nt * 16 + l16] = acc[r];
    }
}

// ---------------- one conv+GRU step: 128 blocks x 1024 threads ----------------
// Block owns 64 nodes; 16 waves: wave w -> column group wc=w&7 (cols [16wc,16wc+16)),
// m-tile pair mh=w>>3 (tiles 2mh, 2mh+1). B-fragment traffic halves vs MT32.
__global__ __launch_bounds__(1024, 1) void k_step(
    float* __restrict__ hF,
    const float* __restrict__ Pprev, float* __restrict__ Pnext,
    const half_t* __restrict__ rootP, const half_t* __restrict__ WihP,
    const half_t* __restrict__ WhhP, const half_t* __restrict__ bondTP,
    const half_t* __restrict__ bondQP,
    const float* __restrict__ cbias, const float* __restrict__ bih,
    const float* __restrict__ bhh,
    const int4* __restrict__ epack,
    const int* __restrict__ row_start, const float* __restrict__ inv_deg, int writeP) {
    __shared__ __align__(16) half_t As[SMT * LDA];
    __shared__ __align__(16) half_t Am[SMT * LDA];
    __shared__ __align__(16) half_t Qh[SMT * LDQ];
    __shared__ float Q[SMT * 32];

    const int tid = threadIdx.x;
    const int w = tid >> 6;
    const int lane = tid & 63;
    const int quad = lane >> 4;
    const int l16 = lane & 15;
    const int wc = w & 7;        // column group
    const int mh = w >> 3;       // m-tile pair (0/1)
    const int n0 = blockIdx.x * SMT;
    const int c = wc * 16 + l16;

    // --- phase A: stage h (2 float4/thread), hold loads, Q zero, edge gather ---
    {
        int row = tid >> 4;              // 64 rows
        int col = (tid & 15) * 8;
        const float* src = hF + (size_t)(n0 + row) * D + col;
        float4 v0 = ((const float4*)src)[0];
        float4 v1 = ((const float4*)src)[1];
        f16x8 hv;
        hv[0] = (half_t)v0.x; hv[1] = (half_t)v0.y; hv[2] = (half_t)v0.z; hv[3] = (half_t)v0.w;
        hv[4] = (half_t)v1.x; hv[5] = (half_t)v1.y; hv[6] = (half_t)v1.z; hv[7] = (half_t)v1.w;
        *(f16x8*)&As[row * LDA + col] = hv;
    }
    float hold[2][4];
#pragma unroll
    for (int mt = 0; mt < 2; ++mt)
#pragma unroll
        for (int r = 0; r < 4; ++r)
            hold[mt][r] = hF[(size_t)(n0 + (mh * 2 + mt) * 16 + quad * 4 + r) * D + c];
    Q[tid] = 0.f;
    Q[tid + 1024] = 0.f;
    const int p0 = row_start[n0];
    const int p1 = row_start[n0 + SMT];
    int4 ep;
    float wv = 0.f, idg = 0.f;
    const int pme = p0 + tid;
    const bool have = (pme < p1);
    if (have) {
        ep = epack[pme];
        wv = Pprev[(size_t)ep.x * 32 + ep.y];
        idg = inv_deg[ep.w];
    }
    f16x8 aggB = *(const f16x8*)(bondQP + (size_t)(wc * 64 + lane) * 8);
    const float cb = cbias[c];
    const float bi0 = bih[c], bi1 = bih[D + c], bi2 = bih[2 * D + c];
    const float bh0 = bhh[c], bh1 = bhh[D + c], bh2 = bhh[2 * D + c];
    __syncthreads();

    // --- phase B: conv + gh MFMAs (B streamed); Q atomics overlap ---
    f32x4 convAcc[2] = {{0.f, 0.f, 0.f, 0.f}, {0.f, 0.f, 0.f, 0.f}};
#pragma unroll
    for (int kt = 0; kt < 4; ++kt) {
        f16x8 b = *(const f16x8*)(rootP + (size_t)((wc * 4 + kt) * 64 + lane) * 8);
        f16x8 a0 = *(const f16x8*)&As[((mh * 2 + 0) * 16 + l16) * LDA + kt * 32 + quad * 8];
        f16x8 a1 = *(const f16x8*)&As[((mh * 2 + 1) * 16 + l16) * LDA + kt * 32 + quad * 8];
        convAcc[0] = __builtin_amdgcn_mfma_f32_16x16x32_f16(a0, b, convAcc[0], 0, 0, 0);
        convAcc[1] = __builtin_amdgcn_mfma_f32_16x16x32_f16(a1, b, convAcc[1], 0, 0, 0);
    }
    if (have) atomicAdd(&Q[(ep.w - n0) * 32 + ep.z], wv * idg);
    for (int p2 = pme + 1024; p2 < p1; p2 += 1024) {   // overflow (rare)
        int4 e2 = epack[p2];
        atomicAdd(&Q[(e2.w - n0) * 32 + e2.z], Pprev[(size_t)e2.x * 32 + e2.y] * inv_deg[e2.w]);
    }
    f32x4 ghA[2][3];
#pragma unroll
    for (int mt = 0; mt < 2; ++mt)
#pragma unroll
        for (int g = 0; g < 3; ++g) ghA[mt][g] = f32x4{0.f, 0.f, 0.f, 0.f};
#pragma unroll
    for (int kt = 0; kt < 4; ++kt) {
        f16x8 a0 = *(const f16x8*)&As[((mh * 2 + 0) * 16 + l16) * LDA + kt * 32 + quad * 8];
        f16x8 a1 = *(const f16x8*)&As[((mh * 2 + 1) * 16 + l16) * LDA + kt * 32 + quad * 8];
#pragma unroll
        for (int g = 0; g < 3; ++g) {
            f16x8 b = *(const f16x8*)(WhhP + (size_t)(((g * 8 + wc) * 4 + kt) * 64 + lane) * 8);
            ghA[0][g] = __builtin_amdgcn_mfma_f32_16x16x32_f16(a0, b, ghA[0][g], 0, 0, 0);
            ghA[1][g] = __builtin_amdgcn_mfma_f32_16x16x32_f16(a1, b, ghA[1][g], 0, 0, 0);
        }
    }
    __syncthreads();   // Q complete

    // --- convert Q -> fp16 (idg applied at gather) ---
    Qh[(tid >> 5) * LDQ + (tid & 31)] = (half_t)Q[tid];
    Qh[((tid + 1024) >> 5) * LDQ + (tid & 31)] = (half_t)Q[tid + 1024];
    __syncthreads();

    // --- agg MFMA + m -> Am ---
#pragma unroll
    for (int mt = 0; mt < 2; ++mt) {
        f32x4 acc = {0.f, 0.f, 0.f, 0.f};
        f16x8 a = *(const f16x8*)&Qh[((mh * 2 + mt) * 16 + l16) * LDQ + quad * 8];
        acc = __builtin_amdgcn_mfma_f32_16x16x32_f16(a, aggB, acc, 0, 0, 0);
#pragma unroll
        for (int r = 0; r < 4; ++r) {
            float m = convAcc[mt][r] + cb + acc[r];
            Am[((mh * 2 + mt) * 16 + quad * 4 + r) * LDA + c] = (half_t)leaky(m);
        }
    }
    __syncthreads();

    // --- gi MFMAs (B streamed) + GRU combine ---
    f32x4 giA[2][3];
#pragma unroll
    for (int mt = 0; mt < 2; ++mt)
#pragma unroll
        for (int g = 0; g < 3; ++g) giA[mt][g] = f32x4{0.f, 0.f, 0.f, 0.f};
#pragma unroll
    for (int kt = 0; kt < 4; ++kt) {
        f16x8 a0 = *(const f16x8*)&Am[((mh * 2 + 0) * 16 + l16) * LDA + kt * 32 + quad * 8];
        f16x8 a1 = *(const f16x8*)&Am[((mh * 2 + 1) * 16 + l16) * LDA + kt * 32 + quad * 8];
#pragma unroll
        for (int g = 0; g < 3; ++g) {
            f16x8 b = *(const f16x8*)(WihP + (size_t)(((g * 8 + wc) * 4 + kt) * 64 + lane) * 8);
            giA[0][g] = __builtin_amdgcn_mfma_f32_16x16x32_f16(a0, b, giA[0][g], 0, 0, 0);
            giA[1][g] = __builtin_amdgcn_mfma_f32_16x16x32_f16(a1, b, giA[1][g], 0, 0, 0);
        }
    }
#pragma unroll
    for (int mt = 0; mt < 2; ++mt) {
#pragma unroll
        for (int r = 0; r < 4; ++r) {
            int row = (mh * 2 + mt) * 16 + quad * 4 + r;
            float rg = fast_sigmoid(giA[mt][0][r] + bi0 + ghA[mt][0][r] + bh0);
            float z = fast_sigmoid(giA[mt][1][r] + bi1 + ghA[mt][1][r] + bh1);
            float nn = fast_tanh(giA[mt][2][r] + bi2 + rg * (ghA[mt][2][r] + bh2));
            float hnew = (1.f - z) * nn + z * hold[mt][r];
            hF[(size_t)(n0 + row) * D + c] = hnew;
            As[row * LDA + c] = (half_t)hnew;
        }
    }

    if (writeP) {
        __syncthreads();
        if (w < 8) {   // P tile: 4 m-tiles x 2 col-halves
            int mt = w >> 1, nt = w & 1;
            f32x4 acc = {0.f, 0.f, 0.f, 0.f};
#pragma unroll
            for (int kt = 0; kt < 4; ++kt) {
                f16x8 b = *(const f16x8*)(bondTP + (size_t)((nt * 4 + kt) * 64 + lane) * 8);
                f16x8 a = *(const f16x8*)&As[(mt * 16 + l16) * LDA + kt * 32 + quad * 8];
                acc = __builtin_amdgcn_mfma_f32_16x16x32_f16(a, b, acc, 0, 0, 0);
            }
#pragma unroll
            for (int r = 0; r < 4; ++r)
                Pnext[(size_t)(n0 + mt * 16 + quad * 4 + r) * 32 + nt * 16 + l16] = acc[r];
        }
    }
}

// ---------------- stem head (MFMA) + fused gpred ----------------
__device__ __forceinline__ int lower_bound_dev(const int* a, int n, int v) {
    int lo = 0, hi = n;
    while (lo < hi) {
        int m = (lo + hi) >> 1;
        if (a[m] < v) lo = m + 1;
        else hi = m;
    }
    return lo;
}

__global__ __launch_bounds__(512) void k_heads(
    const float* __restrict__ hF, const int* __restrict__ sni, const int* __restrict__ stypes,
    const float* __restrict__ embStem,
    const half_t* __restrict__ s1P, const float* __restrict__ b1,
    const half_t* __restrict__ s2P, const float* __restrict__ b2,
    const half_t* __restrict__ s3P, const float* __restrict__ b3,
    const int* __restrict__ batch,
    const float* __restrict__ g1T, const float* __restrict__ gb1,
    const float* __restrict__ gw2, const float* __restrict__ gb2,
    float* __restrict__ dout) {
    __shared__ __align__(16) half_t cat[16 * LDA2];
    __shared__ __align__(16) half_t t1[16 * LDA];
    __shared__ __align__(16) half_t t2[16 * LDA];
    const int tid = threadIdx.x;
    if (blockIdx.x >= 256) {
        int g = blockIdx.x - 256;
        if (tid >= 128) return;
        __shared__ float mean_s[D];
        __shared__ float red[D];
        int j = tid;
        int lo = lower_bound_dev(batch, NNODES, g);
        int hi = lower_bound_dev(batch, NNODES, g + 1);
        float sum = 0.f;
        for (int n = lo; n < hi; ++n) sum += hF[(size_t)n * D + j];
        float denom = (hi > lo) ? (float)(hi - lo) : 1.0f;
        mean_s[j] = sum / denom;
        __syncthreads();
        float a = gb1[j];
        for (int i = 0; i < D; ++i) a += mean_s[i] * g1T[i * D + j];
        a = leaky(a);
        red[j] = a * gw2[j];
        __syncthreads();
        for (int off = 64; off > 0; off >>= 1) {
            if (j < off) red[j] += red[j + off];
            __syncthreads();
        }
        if (j == 0) dout[NSTEMS * OPS + g] = red[0] + gb2[0];
        return;
    }
    const int w = tid >> 6;
    const int lane = tid & 63;
    const int quad = lane >> 4;
    const int l16 = lane & 15;
    const int s0 = blockIdx.x * 16;
    const int c = w * 16 + l16;

    {
        int row = tid >> 5;
        int col = (tid & 31) * 8;
        const float* src;
        if (col < D) src = hF + (size_t)sni[s0 + row] * D + col;
        else src = embStem + (size_t)stypes[s0 + row] * D + (col - D);
        float4 v0 = ((const float4*)src)[0];
        float4 v1 = ((const float4*)src)[1];
        f16x8 hv;
        hv[0] = (half_t)v0.x; hv[1] = (half_t)v0.y; hv[2] = (half_t)v0.z; hv[3] = (half_t)v0.w;
        hv[4] = (half_t)v1.x; hv[5] = (half_t)v1.y; hv[6] = (half_t)v1.z; hv[7] = (half_t)v1.w;
        *(f16x8*)&cat[row * LDA2 + col] = hv;
    }
    __syncthreads();

    {
        f32x4 acc = {0.f, 0.f, 0.f, 0.f};
#pragma unroll
        for (int kt = 0; kt < 8; ++kt) {
            f16x8 b = *(const f16x8*)(s1P + (size_t)((w * 8 + kt) * 64 + lane) * 8);
            f16x8 a = *(const f16x8*)&cat[l16 * LDA2 + kt * 32 + quad * 8];
            acc = __builtin_amdgcn_mfma_f32_16x16x32_f16(a, b, acc, 0, 0, 0);
        }
        float bb = b1[c];
#pragma unroll
        for (int r = 0; r < 4; ++r)
            t1[(quad * 4 + r) * LDA + c] = (half_t)leaky(acc[r] + bb);
    }
    __syncthreads();
    {
        f32x4 acc = {0.f, 0.f, 0.f, 0.f};
#pragma unroll
        for (int kt = 0; kt < 4; ++kt) {
            f16x8 b = *(const f16x8*)(s2P + (size_t)((w * 4 + kt) * 64 + lane) * 8);
            f16x8 a = *(const f16x8*)&t1[l16 * LDA + kt * 32 + quad * 8];
            acc = __builtin_amdgcn_mfma_f32_16x16x32_f16(a, b, acc, 0, 0, 0);
        }
        float bb = b2[c];
#pragma unroll
        for (int r = 0; r < 4; ++r)
            t2[(quad * 4 + r) * LDA + c] = (half_t)leaky(acc[r] + bb);
    }
    __syncthreads();
    if (w < 7) {
        f32x4 acc = {0.f, 0.f, 0.f, 0.f};
#pragma unroll
        for (int kt = 0; kt < 4; ++kt) {
            f16x8 b = *(const f16x8*)(s3P + (size_t)((w * 4 + kt) * 64 + lane) * 8);
            f16x8 a = *(const f16x8*)&t2[l16 * LDA + kt * 32 + quad * 8];
            acc = __builtin_amdgcn_mfma_f32_16x16x32_f16(a, b, acc, 0, 0, 0);
        }
        int j = w * 16 + l16;
        if (j < OPS) {
            float bb = b3[j];
#pragma unroll
            for (int r = 0; r < 4; ++r)
                dout[(size_t)(s0 + quad * 4 + r) * OPS + j] = acc[r] + bb;
        }
    }
}

// ---------------- launch ----------------
extern "C" void kernel_launch(void* const* d_in, const int* in_sizes, int n_in,
                              void* d_out, int out_size, void* d_ws, size_t ws_size,
                              hipStream_t stream) {
    const int* x = (const int*)d_in[0];
    const int* stypes = (const int*)d_in[1];
    const int* eattr = (const int*)d_in[2];
    const int* eidx = (const int*)d_in[3];
    const int* sni = (const int*)d_in[4];
    const int* batch = (const int*)d_in[5];
    const float* embBlock = (const float*)d_in[6];
    const float* embStem = (const float*)d_in[7];
    const float* embBond = (const float*)d_in[8];
    const float* b2e_w1 = (const float*)d_in[9];
    const float* b2e_b1 = (const float*)d_in[10];
    const float* b2e_w2 = (const float*)d_in[11];
    const float* b2e_b2 = (const float*)d_in[12];
    const float* conv_root = (const float*)d_in[13];
    const float* conv_bias = (const float*)d_in[14];
    const float* gru_w_ih = (const float*)d_in[15];
    const float* gru_w_hh = (const float*)d_in[16];
    const float* gru_b_ih = (const float*)d_in[17];
    const float* gru_b_hh = (const float*)d_in[18];
    const float* s2p_w1 = (const float*)d_in[19];
    const float* s2p_b1 = (const float*)d_in[20];
    const float* s2p_w2 = (const float*)d_in[21];
    const float* s2p_b2 = (const float*)d_in[22];
    const float* s2p_w3 = (const float*)d_in[23];
    const float* s2p_b3 = (const float*)d_in[24];
    const float* g2p_w1 = (const float*)d_in[25];
    const float* g2p_b1 = (const float*)d_in[26];
    const float* g2p_w2 = (const float*)d_in[27];
    const float* g2p_b2 = (const float*)d_in[28];
    float* out_f = (float*)d_out;

    float* W = (float*)d_ws;
    size_t off = 0;
    auto alloc = [&](size_t words) {
        size_t o = off;
        off += (words + 3) & ~(size_t)3;
        return o;
    };
    float* hF = W + alloc(NNODES * D);
    float* P0 = W + alloc(NNODES * 32);
    float* P1 = W + alloc(NNODES * 32);
    half_t* rootP = (half_t*)(W + alloc(16384 / 2));
    half_t* WihP = (half_t*)(W + alloc(49152 / 2));
    half_t* WhhP = (half_t*)(W + alloc(49152 / 2));
    half_t* bondTP = (half_t*)(W + alloc(4096 / 2));
    half_t* s1P = (half_t*)(W + alloc(32768 / 2));
    half_t* s2P = (half_t*)(W + alloc(16384 / 2));
    half_t* s3P = (half_t*)(W + alloc(14336 / 2));
    half_t* w1P = (half_t*)(W + alloc(16384 / 2));
    half_t* w2P = (half_t*)(W + alloc(16384 / 2));
    half_t* bondQP = (half_t*)(W + alloc(4096 / 2));
    float* g1T = W + alloc(128 * 128);
    int* row_start = (int*)(W + alloc(NNODES + 1));
    int4* epack = (int4*)(W + alloc(NEDGES * 4));
    float* inv_deg = W + alloc(NNODES);
    float* zbase = W + alloc(2 * NNODES);   // deg + fill
    int* deg = (int*)zbase;
    int* fill = deg + NNODES;

    k_setup<<<dim3(192, 12), 256, 0, stream>>>(
        conv_root, gru_w_ih, gru_w_hh, embBond, s2p_w1, s2p_w2, s2p_w3,
        b2e_w1, b2e_w2, g2p_w1,
        rootP, WihP, WhhP, bondTP, s1P, s2P, s3P, w1P, w2P, bondQP,
        g1T, (int*)zbase);
    k_deg<<<(NEDGES + 255) / 256, 256, 0, stream>>>(eidx, deg);
    k_scan<<<1, 256, 0, stream>>>(deg, row_start, inv_deg);
    k_scatter<<<(NEDGES + 255) / 256, 256, 0, stream>>>(eidx, eattr, row_start, fill, epack);
    k_init<<<NNODES / IMT, 512, 0, stream>>>(x, embBlock, w1P, b2e_b1, w2P, b2e_b2,
                                             bondTP, hF, P0);

    for (int step = 0; step < NSTEPS; ++step) {
        const float* Pprev = (step & 1) ? P1 : P0;
        float* Pnext = (step & 1) ? P0 : P1;
        int writeP = (step < NSTEPS - 1) ? 1 : 0;
        k_step<<<NSB, 1024, 0, stream>>>(
            hF, Pprev, Pnext, rootP, WihP, WhhP, bondTP, bondQP,
            conv_bias, gru_b_ih, gru_b_hh,
            epack, row_start, inv_deg, writeP);
    }

    k_heads<<<NSTEMS / 16 + NGRAPHS, 512, 0, stream>>>(
        hF, sni, stypes, embStem,
        s1P, s2p_b1, s2P, s2p_b2, s3P, s2p_b3,
        batch, g1T, g2p_b1, g2p_w2, g2p_b2, out_f);
}

// Round 12
// 260.848 us; speedup vs baseline: 1.2396x; 1.0866x over previous
//
#include <hip/hip_runtime.h>
#include <math.h>

#define D 128
#define NNODES 8192
#define NEDGES 16384
#define NSTEMS 4096
#define NGRAPHS 256
#define NSTEPS 12
#define OPS 105
#define SLOPE 0.01f
#define MT 32              // nodes per step-block (measured optimum)
#define NB (NNODES / MT)   // 256 blocks
#define LDA 136            // padded halfs per LDS row (h/m tiles)
#define LDA2 264           // padded halfs per LDS row (stem cat tile)
#define LDQ 40             // padded halfs per Qh row

typedef _Float16 half_t;
typedef __attribute__((ext_vector_type(8))) _Float16 f16x8;
typedef __attribute__((ext_vector_type(4))) float f32x4;

__device__ __forceinline__ float leaky(float x) { return x > 0.f ? x : SLOPE * x; }
__device__ __forceinline__ float fast_sigmoid(float x) {
    return __builtin_amdgcn_rcpf(1.f + __expf(-x));
}
__device__ __forceinline__ float fast_tanh(float x) {
    float e = __expf(2.f * x);
    return 1.f - 2.f * __builtin_amdgcn_rcpf(e + 1.f);
}

// ---------------- setup: pack weights + transpose g1 ----------------
// B-frag 16x16x32: lane L supplies B[k = kt*32 + (L>>4)*8 + j][n = nt*16 + (L&15)], j=0..7.
__global__ void k_setup(
    const float* __restrict__ root, const float* __restrict__ wih,
    const float* __restrict__ whh, const float* __restrict__ bond,
    const float* __restrict__ sw1, const float* __restrict__ sw2,
    const float* __restrict__ sw3, const float* __restrict__ bw1,
    const float* __restrict__ bw2, const float* __restrict__ gw1,
    half_t* __restrict__ rootP, half_t* __restrict__ WihP,
    half_t* __restrict__ WhhP, half_t* __restrict__ bondTP,
    half_t* __restrict__ s1P, half_t* __restrict__ s2P, half_t* __restrict__ s3P,
    half_t* __restrict__ w1P, half_t* __restrict__ w2P, half_t* __restrict__ bondQP,
    float* __restrict__ g1T) {
    int idx = blockIdx.x * 256 + threadIdx.x;
    int which = blockIdx.y;
    if (which == 10) {
        if (idx < 128 * 128) {
            int r = idx >> 7, c = idx & 127;
            g1T[c * 128 + r] = gw1[idx];
        }
        return;
    }
    int KT = (which == 4) ? 8 : (which == 9) ? 1 : 4;
    int NT = (which == 1 || which == 2) ? 24 : (which == 3) ? 2 : (which == 6) ? 7 : 8;
    if (idx >= NT * KT * 512) return;
    int j = idx & 7;
    int L = (idx >> 3) & 63;
    int t = idx >> 9;
    int kt = t % KT, nt = t / KT;
    int k = kt * 32 + (L >> 4) * 8 + j;
    int n = nt * 16 + (L & 15);
    switch (which) {
        case 0: rootP[idx] = (half_t)root[k * D + n]; break;
        case 1: WihP[idx] = (half_t)wih[n * D + k]; break;
        case 2: WhhP[idx] = (half_t)whh[n * D + k]; break;
        case 3: bondTP[idx] = (half_t)bond[n * D + k]; break;
        case 4: s1P[idx] = (half_t)sw1[n * 256 + k]; break;
        case 5: s2P[idx] = (half_t)sw2[n * 128 + k]; break;
        case 6: s3P[idx] = (n < OPS) ? (half_t)sw3[n * 128 + k] : (half_t)0.f; break;
        case 7: w1P[idx] = (half_t)bw1[n * D + k]; break;
        case 8: w2P[idx] = (half_t)bw2[n * D + k]; break;
        case 9: bondQP[idx] = (half_t)bond[k * D + n]; break;
    }
}

// ---------------- CSR build in ONE kernel (single block, LDS counters) ----------------
// epack[pos] = {src, a0, a1, dst} in CSR order.
__global__ __launch_bounds__(1024) void k_csr(
    const int* __restrict__ eidx, const int* __restrict__ eattr,
    int* __restrict__ row_start, float* __restrict__ inv_deg,
    int4* __restrict__ epack) {
    __shared__ int sdeg[NNODES];     // 32 KB
    __shared__ int sums[1024];       // 4 KB
    const int tid = threadIdx.x;
    for (int i = tid; i < NNODES; i += 1024) sdeg[i] = 0;
    __syncthreads();
    for (int e = tid; e < NEDGES; e += 1024)
        atomicAdd(&sdeg[eidx[NEDGES + e]], 1);
    __syncthreads();
    const int base = tid * 8;
    int s = 0;
#pragma unroll
    for (int k = 0; k < 8; ++k) s += sdeg[base + k];
    sums[tid] = s;
    __syncthreads();
    for (int off = 1; off < 1024; off <<= 1) {
        int v = sums[tid];
        int u = (tid >= off) ? sums[tid - off] : 0;
        __syncthreads();
        sums[tid] = v + u;
        __syncthreads();
    }
    int run = sums[tid] - s;         // exclusive prefix of this thread's chunk
#pragma unroll
    for (int k = 0; k < 8; ++k) {
        int d = sdeg[base + k];
        row_start[base + k] = run;
        inv_deg[base + k] = (d > 0) ? (1.0f / (float)d) : 0.0f;
        sdeg[base + k] = run;        // becomes the fill cursor
        run += d;
    }
    if (tid == 1023) row_start[NNODES] = run;
    __syncthreads();
    for (int e = tid; e < NEDGES; e += 1024) {
        int d = eidx[NEDGES + e];
        int pos = atomicAdd(&sdeg[d], 1);
        int2 aa = *(const int2*)(eattr + 2 * e);
        epack[pos] = make_int4(eidx[e], aa.x, aa.y, d);
    }
}

// ---------------- init (MFMA) + fused P0; writes fp16 h state ----------------
__global__ __launch_bounds__(512, 2) void k_init(
    const int* __restrict__ x, const float* __restrict__ embBlock,
    const half_t* __restrict__ w1P, const float* __restrict__ b1,
    const half_t* __restrict__ w2P, const float* __restrict__ b2,
    const half_t* __restrict__ bondTP,
    half_t* __restrict__ hA, float* __restrict__ P0) {
    __shared__ __align__(16) half_t Ae[MT * LDA];
    __shared__ __align__(16) half_t T1[MT * LDA];
    const int tid = threadIdx.x;
    const int w = tid >> 6;
    const int lane = tid & 63;
    const int quad = lane >> 4;
    const int l16 = lane & 15;
    const int n0 = blockIdx.x * MT;
    const int c = w * 16 + l16;

    {
        int row = tid >> 4;
        int col = (tid & 15) * 8;
        const float* src = embBlock + (size_t)x[n0 + row] * D + col;
        float4 v0 = ((const float4*)src)[0];
        float4 v1 = ((const float4*)src)[1];
        f16x8 hv;
        hv[0] = (half_t)v0.x; hv[1] = (half_t)v0.y; hv[2] = (half_t)v0.z; hv[3] = (half_t)v0.w;
        hv[4] = (half_t)v1.x; hv[5] = (half_t)v1.y; hv[6] = (half_t)v1.z; hv[7] = (half_t)v1.w;
        *(f16x8*)&Ae[row * LDA + col] = hv;
    }
    __syncthreads();

    {
        f32x4 acc[2] = {{0.f, 0.f, 0.f, 0.f}, {0.f, 0.f, 0.f, 0.f}};
#pragma unroll
        for (int kt = 0; kt < 4; ++kt) {
            f16x8 b = *(const f16x8*)(w1P + (size_t)((w * 4 + kt) * 64 + lane) * 8);
            f16x8 a0 = *(const f16x8*)&Ae[(0 + l16) * LDA + kt * 32 + quad * 8];
            f16x8 a1 = *(const f16x8*)&Ae[(16 + l16) * LDA + kt * 32 + quad * 8];
            acc[0] = __builtin_amdgcn_mfma_f32_16x16x32_f16(a0, b, acc[0], 0, 0, 0);
            acc[1] = __builtin_amdgcn_mfma_f32_16x16x32_f16(a1, b, acc[1], 0, 0, 0);
        }
        float bb = b1[c];
#pragma unroll
        for (int mt = 0; mt < 2; ++mt)
#pragma unroll
            for (int r = 0; r < 4; ++r)
                T1[(mt * 16 + quad * 4 + r) * LDA + c] = (half_t)leaky(acc[mt][r] + bb);
    }
    __syncthreads();

    {
        f32x4 acc[2] = {{0.f, 0.f, 0.f, 0.f}, {0.f, 0.f, 0.f, 0.f}};
#pragma unroll
        for (int kt = 0; kt < 4; ++kt) {
            f16x8 b = *(const f16x8*)(w2P + (size_t)((w * 4 + kt) * 64 + lane) * 8);
            f16x8 a0 = *(const f16x8*)&T1[(0 + l16) * LDA + kt * 32 + quad * 8];
            f16x8 a1 = *(const f16x8*)&T1[(16 + l16) * LDA + kt * 32 + quad * 8];
            acc[0] = __builtin_amdgcn_mfma_f32_16x16x32_f16(a0, b, acc[0], 0, 0, 0);
            acc[1] = __builtin_amdgcn_mfma_f32_16x16x32_f16(a1, b, acc[1], 0, 0, 0);
        }
        float bb = b2[c];
#pragma unroll
        for (int mt = 0; mt < 2; ++mt)
#pragma unroll
            for (int r = 0; r < 4; ++r) {
                int row = mt * 16 + quad * 4 + r;
                half_t hh = (half_t)(acc[mt][r] + bb);
                hA[(size_t)(n0 + row) * D + c] = hh;
                Ae[row * LDA + c] = hh;
            }
    }
    __syncthreads();

    if (w < 4) {   // P0 = h0 @ bond^T
        int mt = w >> 1, nt = w & 1;
        f32x4 acc = {0.f, 0.f, 0.f, 0.f};
#pragma unroll
        for (int kt = 0; kt < 4; ++kt) {
            f16x8 b = *(const f16x8*)(bondTP + (size_t)((nt * 4 + kt) * 64 + lane) * 8);
            f16x8 a = *(const f16x8*)&Ae[(mt * 16 + l16) * LDA + kt * 32 + quad * 8];
            acc = __builtin_amdgcn_mfma_f32_16x16x32_f16(a, b, acc, 0, 0, 0);
        }
#pragma unroll
        for (int r = 0; r < 4; ++r)
            P0[(size_t)(n0 + mt * 16 + quad * 4 + r) * 32 + nt * 16 + l16] = acc[r];
    }
}

// ---------------- one conv+GRU step (R6-winning structure, fp16 state) ----------------
// 256 blocks x 512 threads; block owns 32 nodes; wave w owns cols [16w,16w+16).
__global__ __launch_bounds__(512, 2) void k_step(
    const half_t* __restrict__ curH, half_t* __restrict__ nxtH, float* __restrict__ hF,
    const float* __restrict__ Pprev, float* __restrict__ Pnext,
    const half_t* __restrict__ rootP, const half_t* __restrict__ WihP,
    const half_t* __restrict__ WhhP, const half_t* __restrict__ bondTP,
    const half_t* __restrict__ bondQP,
    const float* __restrict__ cbias, const float* __restrict__ bih,
    const float* __restrict__ bhh,
    const int4* __restrict__ epack,
    const int* __restrict__ row_start, const float* __restrict__ inv_deg, int last) {
    __shared__ __align__(16) half_t As[MT * LDA];
    __shared__ __align__(16) half_t Am[MT * LDA];
    __shared__ __align__(16) half_t Qh[MT * LDQ];
    __shared__ float Q[MT * 32];

    const int tid = threadIdx.x;
    const int w = tid >> 6;
    const int lane = tid & 63;
    const int quad = lane >> 4;
    const int l16 = lane & 15;
    const int n0 = blockIdx.x * MT;
    const int c = w * 16 + l16;

    // --- phase A: stage h (one f16x8/thread), zero Q, edge gather, B-frag prefetch ---
    {
        int row = tid >> 4;
        int col = (tid & 15) * 8;
        f16x8 v = *(const f16x8*)(curH + (size_t)(n0 + row) * D + col);
        *(f16x8*)&As[row * LDA + col] = v;
    }
    Q[tid] = 0.f;
    Q[tid + 512] = 0.f;
    const int p0 = row_start[n0];
    const int p1 = row_start[n0 + MT];
    int4 ep;
    float wv = 0.f, idg = 0.f;
    const int pme = p0 + tid;
    const bool have = (pme < p1);
    if (have) {
        ep = epack[pme];
        wv = Pprev[(size_t)ep.x * 32 + ep.y];
        idg = inv_deg[ep.w];
    }
    f16x8 rootB[4], ghB[12], aggB;
#pragma unroll
    for (int kt = 0; kt < 4; ++kt)
        rootB[kt] = *(const f16x8*)(rootP + (size_t)((w * 4 + kt) * 64 + lane) * 8);
#pragma unroll
    for (int kt = 0; kt < 4; ++kt)
#pragma unroll
        for (int g = 0; g < 3; ++g)
            ghB[g * 4 + kt] = *(const f16x8*)(WhhP + (size_t)(((g * 8 + w) * 4 + kt) * 64 + lane) * 8);
    aggB = *(const f16x8*)(bondQP + (size_t)(w * 64 + lane) * 8);
    const float cb = cbias[c];
    const float bi0 = bih[c], bi1 = bih[D + c], bi2 = bih[2 * D + c];
    const float bh0 = bhh[c], bh1 = bhh[D + c], bh2 = bhh[2 * D + c];
    __syncthreads();

    // --- hold (old h) from LDS ---
    float hold[2][4];
#pragma unroll
    for (int mt = 0; mt < 2; ++mt)
#pragma unroll
        for (int r = 0; r < 4; ++r)
            hold[mt][r] = (float)As[(mt * 16 + quad * 4 + r) * LDA + c];

    // --- phase B: conv + gh MFMAs (prefetched B); Q atomics overlap ---
    f32x4 convAcc[2] = {{0.f, 0.f, 0.f, 0.f}, {0.f, 0.f, 0.f, 0.f}};
#pragma unroll
    for (int kt = 0; kt < 4; ++kt) {
        f16x8 a0 = *(const f16x8*)&As[(0 + l16) * LDA + kt * 32 + quad * 8];
        f16x8 a1 = *(const f16x8*)&As[(16 + l16) * LDA + kt * 32 + quad * 8];
        convAcc[0] = __builtin_amdgcn_mfma_f32_16x16x32_f16(a0, rootB[kt], convAcc[0], 0, 0, 0);
        convAcc[1] = __builtin_amdgcn_mfma_f32_16x16x32_f16(a1, rootB[kt], convAcc[1], 0, 0, 0);
    }
    if (have) atomicAdd(&Q[(ep.w - n0) * 32 + ep.z], wv * idg);
    for (int p2 = pme + 512; p2 < p1; p2 += 512) {   // overflow (rare)
        int4 e2 = epack[p2];
        atomicAdd(&Q[(e2.w - n0) * 32 + e2.z], Pprev[(size_t)e2.x * 32 + e2.y] * inv_deg[e2.w]);
    }
    f32x4 ghA[2][3];
#pragma unroll
    for (int mt = 0; mt < 2; ++mt)
#pragma unroll
        for (int g = 0; g < 3; ++g) ghA[mt][g] = f32x4{0.f, 0.f, 0.f, 0.f};
#pragma unroll
    for (int kt = 0; kt < 4; ++kt) {
        f16x8 a0 = *(const f16x8*)&As[(0 + l16) * LDA + kt * 32 + quad * 8];
        f16x8 a1 = *(const f16x8*)&As[(16 + l16) * LDA + kt * 32 + quad * 8];
#pragma unroll
        for (int g = 0; g < 3; ++g) {
            ghA[0][g] = __builtin_amdgcn_mfma_f32_16x16x32_f16(a0, ghB[g * 4 + kt], ghA[0][g], 0, 0, 0);
            ghA[1][g] = __builtin_amdgcn_mfma_f32_16x16x32_f16(a1, ghB[g * 4 + kt], ghA[1][g], 0, 0, 0);
        }
    }
    __syncthreads();   // Q complete

    // --- load gi B-frags (covered by convert/agg phases) ---
    f16x8 giB[12];
#pragma unroll
    for (int kt = 0; kt < 4; ++kt)
#pragma unroll
        for (int g = 0; g < 3; ++g)
            giB[g * 4 + kt] = *(const f16x8*)(WihP + (size_t)(((g * 8 + w) * 4 + kt) * 64 + lane) * 8);

    // --- convert Q -> fp16 ---
    Qh[(tid >> 5) * LDQ + (tid & 31)] = (half_t)Q[tid];
    Qh[((tid + 512) >> 5) * LDQ + (tid & 31)] = (half_t)Q[tid + 512];
    __syncthreads();

    // --- agg MFMA + m -> Am ---
#pragma unroll
    for (int mt = 0; mt < 2; ++mt) {
        f32x4 acc = {0.f, 0.f, 0.f, 0.f};
        f16x8 a = *(const f16x8*)&Qh[(mt * 16 + l16) * LDQ + quad * 8];
        acc = __builtin_amdgcn_mfma_f32_16x16x32_f16(a, aggB, acc, 0, 0, 0);
#pragma unroll
        for (int r = 0; r < 4; ++r) {
            float m = convAcc[mt][r] + cb + acc[r];
            Am[(mt * 16 + quad * 4 + r) * LDA + c] = (half_t)leaky(m);
        }
    }
    __syncthreads();

    // --- gi MFMAs + GRU combine ---
    f32x4 giA[2][3];
#pragma unroll
    for (int mt = 0; mt < 2; ++mt)
#pragma unroll
        for (int g = 0; g < 3; ++g) giA[mt][g] = f32x4{0.f, 0.f, 0.f, 0.f};
#pragma unroll
    for (int kt = 0; kt < 4; ++kt) {
        f16x8 a0 = *(const f16x8*)&Am[(0 + l16) * LDA + kt * 32 + quad * 8];
        f16x8 a1 = *(const f16x8*)&Am[(16 + l16) * LDA + kt * 32 + quad * 8];
#pragma unroll
        for (int g = 0; g < 3; ++g) {
            giA[0][g] = __builtin_amdgcn_mfma_f32_16x16x32_f16(a0, giB[g * 4 + kt], giA[0][g], 0, 0, 0);
            giA[1][g] = __builtin_amdgcn_mfma_f32_16x16x32_f16(a1, giB[g * 4 + kt], giA[1][g], 0, 0, 0);
        }
    }
#pragma unroll
    for (int mt = 0; mt < 2; ++mt) {
#pragma unroll
        for (int r = 0; r < 4; ++r) {
            int row = mt * 16 + quad * 4 + r;
            float rg = fast_sigmoid(giA[mt][0][r] + bi0 + ghA[mt][0][r] + bh0);
            float z = fast_sigmoid(giA[mt][1][r] + bi1 + ghA[mt][1][r] + bh1);
            float nn = fast_tanh(giA[mt][2][r] + bi2 + rg * (ghA[mt][2][r] + bh2));
            float hnew = (1.f - z) * nn + z * hold[mt][r];
            if (last) {
                hF[(size_t)(n0 + row) * D + c] = hnew;
            } else {
                half_t hh = (half_t)hnew;
                nxtH[(size_t)(n0 + row) * D + c] = hh;
                As[row * LDA + c] = hh;
            }
        }
    }

    if (!last) {
        __syncthreads();
        if (w < 4) {   // P_next = h_new @ bond^T
            int mt = w >> 1, nt = w & 1;
            f32x4 acc = {0.f, 0.f, 0.f, 0.f};
#pragma unroll
            for (int kt = 0; kt < 4; ++kt) {
                f16x8 b = *(const f16x8*)(bondTP + (size_t)((nt * 4 + kt) * 64 + lane) * 8);
                f16x8 a = *(const f16x8*)&As[(mt * 16 + l16) * LDA + kt * 32 + quad * 8];
                acc = __builtin_amdgcn_mfma_f32_16x16x32_f16(a, b, acc, 0, 0, 0);
            }
#pragma unroll
            for (int r = 0; r < 4; ++r)
                Pnext[(size_t)(n0 + mt * 16 + quad * 4 + r) * 32 + nt * 16 + l16] = acc[r];
        }
    }
}

// ---------------- stem head (MFMA) + fused gpred ----------------
__device__ __forceinline__ int lower_bound_dev(const int* a, int n, int v) {
    int lo = 0, hi = n;
    while (lo < hi) {
        int m = (lo + hi) >> 1;
        if (a[m] < v) lo = m + 1;
        else hi = m;
    }
    return lo;
}

__global__ __launch_bounds__(512) void k_heads(
    const float* __restrict__ hF, const int* __restrict__ sni, const int* __restrict__ stypes,
    const float* __restrict__ embStem,
    const half_t* __restrict__ s1P, const float* __restrict__ b1,
    const half_t* __restrict__ s2P, const float* __restrict__ b2,
    const half_t* __restrict__ s3P, const float* __restrict__ b3,
    const int* __restrict__ batch,
    const float* __restrict__ g1T, const float* __restrict__ gb1,
    const float* __restrict__ gw2, const float* __restrict__ gb2,
    float* __restrict__ dout) {
    __shared__ __align__(16) half_t cat[16 * LDA2];
    __shared__ __align__(16) half_t t1[16 * LDA];
    __shared__ __align__(16) half_t t2[16 * LDA];
    const int tid = threadIdx.x;
    if (blockIdx.x >= 256) {
        int g = blockIdx.x - 256;
        if (tid >= 128) return;
        __shared__ float mean_s[D];
        __shared__ float red[D];
        int j = tid;
        int lo = lower_bound_dev(batch, NNODES, g);
        int hi = lower_bound_dev(batch, NNODES, g + 1);
        float sum = 0.f;
        for (int n = lo; n < hi; ++n) sum += hF[(size_t)n * D + j];
        float denom = (hi > lo) ? (float)(hi - lo) : 1.0f;
        mean_s[j] = sum / denom;
        __syncthreads();
        float a = gb1[j];
        for (int i = 0; i < D; ++i) a += mean_s[i] * g1T[i * D + j];
        a = leaky(a);
        red[j] = a * gw2[j];
        __syncthreads();
        for (int off = 64; off > 0; off >>= 1) {
            if (j < off) red[j] += red[j + off];
            __syncthreads();
        }
        if (j == 0) dout[NSTEMS * OPS + g] = red[0] + gb2[0];
        return;
    }
    const int w = tid >> 6;
    const int lane = tid & 63;
    const int quad = lane >> 4;
    const int l16 = lane & 15;
    const int s0 = blockIdx.x * 16;
    const int c = w * 16 + l16;

    {
        int row = tid >> 5;
        int col = (tid & 31) * 8;
        const float* src;
        if (col < D) src = hF + (size_t)sni[s0 + row] * D + col;
        else src = embStem + (size_t)stypes[s0 + row] * D + (col - D);
        float4 v0 = ((const float4*)src)[0];
        float4 v1 = ((const float4*)src)[1];
        f16x8 hv;
        hv[0] = (half_t)v0.x; hv[1] = (half_t)v0.y; hv[2] = (half_t)v0.z; hv[3] = (half_t)v0.w;
        hv[4] = (half_t)v1.x; hv[5] = (half_t)v1.y; hv[6] = (half_t)v1.z; hv[7] = (half_t)v1.w;
        *(f16x8*)&cat[row * LDA2 + col] = hv;
    }
    __syncthreads();

    {
        f32x4 acc = {0.f, 0.f, 0.f, 0.f};
#pragma unroll
        for (int kt = 0; kt < 8; ++kt) {
            f16x8 b = *(const f16x8*)(s1P + (size_t)((w * 8 + kt) * 64 + lane) * 8);
            f16x8 a = *(const f16x8*)&cat[l16 * LDA2 + kt * 32 + quad * 8];
            acc = __builtin_amdgcn_mfma_f32_16x16x32_f16(a, b, acc, 0, 0, 0);
        }
        float bb = b1[c];
#pragma unroll
        for (int r = 0; r < 4; ++r)
            t1[(quad * 4 + r) * LDA + c] = (half_t)leaky(acc[r] + bb);
    }
    __syncthreads();
    {
        f32x4 acc = {0.f, 0.f, 0.f, 0.f};
#pragma unroll
        for (int kt = 0; kt < 4; ++kt) {
            f16x8 b = *(const f16x8*)(s2P + (size_t)((w * 4 + kt) * 64 + lane) * 8);
            f16x8 a = *(const f16x8*)&t1[l16 * LDA + kt * 32 + quad * 8];
            acc = __builtin_amdgcn_mfma_f32_16x16x32_f16(a, b, acc, 0, 0, 0);
        }
        float bb = b2[c];
#pragma unroll
        for (int r = 0; r < 4; ++r)
            t2[(quad * 4 + r) * LDA + c] = (half_t)leaky(acc[r] + bb);
    }
    __syncthreads();
    if (w < 7) {
        f32x4 acc = {0.f, 0.f, 0.f, 0.f};
#pragma unroll
        for (int kt = 0; kt < 4; ++kt) {
            f16x8 b = *(const f16x8*)(s3P + (size_t)((w * 4 + kt) * 64 + lane) * 8);
            f16x8 a = *(const f16x8*)&t2[l16 * LDA + kt * 32 + quad * 8];
            acc = __builtin_amdgcn_mfma_f32_16x16x32_f16(a, b, acc, 0, 0, 0);
        }
        int j = w * 16 + l16;
        if (j < OPS) {
            float bb = b3[j];
#pragma unroll
            for (int r = 0; r < 4; ++r)
                dout[(size_t)(s0 + quad * 4 + r) * OPS + j] = acc[r] + bb;
        }
    }
}

// ---------------- launch ----------------
extern "C" void kernel_launch(void* const* d_in, const int* in_sizes, int n_in,
                              void* d_out, int out_size, void* d_ws, size_t ws_size,
                              hipStream_t stream) {
    const int* x = (const int*)d_in[0];
    const int* stypes = (const int*)d_in[1];
    const int* eattr = (const int*)d_in[2];
    const int* eidx = (const int*)d_in[3];
    const int* sni = (const int*)d_in[4];
    const int* batch = (const int*)d_in[5];
    const float* embBlock = (const float*)d_in[6];
    const float* embStem = (const float*)d_in[7];
    const float* embBond = (const float*)d_in[8];
    const float* b2e_w1 = (const float*)d_in[9];
    const float* b2e_b1 = (const float*)d_in[10];
    const float* b2e_w2 = (const float*)d_in[11];
    const float* b2e_b2 = (const float*)d_in[12];
    const float* conv_root = (const float*)d_in[13];
    const float* conv_bias = (const float*)d_in[14];
    const float* gru_w_ih = (const float*)d_in[15];
    const float* gru_w_hh = (const float*)d_in[16];
    const float* gru_b_ih = (const float*)d_in[17];
    const float* gru_b_hh = (const float*)d_in[18];
    const float* s2p_w1 = (const float*)d_in[19];
    const float* s2p_b1 = (const float*)d_in[20];
    const float* s2p_w2 = (const float*)d_in[21];
    const float* s2p_b2 = (const float*)d_in[22];
    const float* s2p_w3 = (const float*)d_in[23];
    const float* s2p_b3 = (const float*)d_in[24];
    const float* g2p_w1 = (const float*)d_in[25];
    const float* g2p_b1 = (const float*)d_in[26];
    const float* g2p_w2 = (const float*)d_in[27];
    const float* g2p_b2 = (const float*)d_in[28];
    float* out_f = (float*)d_out;

    float* W = (float*)d_ws;
    size_t off = 0;
    auto alloc = [&](size_t words) {
        size_t o = off;
        off += (words + 3) & ~(size_t)3;
        return o;
    };
    float* hF = W + alloc(NNODES * D);
    half_t* hA = (half_t*)(W + alloc(NNODES * D / 2));
    half_t* hB = (half_t*)(W + alloc(NNODES * D / 2));
    float* P0 = W + alloc(NNODES * 32);
    float* P1 = W + alloc(NNODES * 32);
    half_t* rootP = (half_t*)(W + alloc(16384 / 2));
    half_t* WihP = (half_t*)(W + alloc(49152 / 2));
    half_t* WhhP = (half_t*)(W + alloc(49152 / 2));
    half_t* bondTP = (half_t*)(W + alloc(4096 / 2));
    half_t* s1P = (half_t*)(W + alloc(32768 / 2));
    half_t* s2P = (half_t*)(W + alloc(16384 / 2));
    half_t* s3P = (half_t*)(W + alloc(14336 / 2));
    half_t* w1P = (half_t*)(W + alloc(16384 / 2));
    half_t* w2P = (half_t*)(W + alloc(16384 / 2));
    half_t* bondQP = (half_t*)(W + alloc(4096 / 2));
    float* g1T = W + alloc(128 * 128);
    int* row_start = (int*)(W + alloc(NNODES + 1));
    int4* epack = (int4*)(W + alloc(NEDGES * 4));
    float* inv_deg = W + alloc(NNODES);

    k_setup<<<dim3(192, 11), 256, 0, stream>>>(
        conv_root, gru_w_ih, gru_w_hh, embBond, s2p_w1, s2p_w2, s2p_w3,
        b2e_w1, b2e_w2, g2p_w1,
        rootP, WihP, WhhP, bondTP, s1P, s2P, s3P, w1P, w2P, bondQP, g1T);
    k_csr<<<1, 1024, 0, stream>>>(eidx, eattr, row_start, inv_deg, epack);
    k_init<<<NNODES / MT, 512, 0, stream>>>(x, embBlock, w1P, b2e_b1, w2P, b2e_b2,
                                            bondTP, hA, P0);

    for (int step = 0; step < NSTEPS; ++step) {
        const half_t* cur = (step & 1) ? hB : hA;
        half_t* nxt = (step & 1) ? hA : hB;
        const float* Pprev = (step & 1) ? P1 : P0;
        float* Pnext = (step & 1) ? P0 : P1;
        int last = (step == NSTEPS - 1) ? 1 : 0;
        k_step<<<NB, 512, 0, stream>>>(
            cur, nxt, hF, Pprev, Pnext, rootP, WihP, WhhP, bondTP, bondQP,
            conv_bias, gru_b_ih, gru_b_hh,
            epack, row_start, inv_deg, last);
    }

    k_heads<<<NSTEMS / 16 + NGRAPHS, 512, 0, stream>>>(
        hF, sni, stypes, embStem,
        s1P, s2p_b1, s2P, s2p_b2, s3P, s2p_b3,
        batch, g1T, g2p_b1, g2p_w2, g2p_b2, out_f);
}